// Round 2
// baseline (993.781 us; speedup 1.0000x reference)
//
#include <hip/hip_runtime.h>
#include <hip/hip_bf16.h>

#define B_ 2
#define S_ 4096
#define D_ 512
#define H_ 8
#define HD_ 64
#define FF_ 2048
#define NT_ (B_*S_)
#define EPS_ 1e-5f

typedef __attribute__((ext_vector_type(8))) short bf16x8;
typedef __attribute__((ext_vector_type(4))) float f32x4;

__device__ __forceinline__ short f2bf(float f){
  __hip_bfloat16 h = __float2bfloat16(f);
  return __builtin_bit_cast(short, h);
}
__device__ __forceinline__ float bf2f(short s){
  return __bfloat162float(__builtin_bit_cast(__hip_bfloat16, s));
}
__device__ __forceinline__ void load8(const float* p, float* f){
  f32x4 a = *(const f32x4*)p; f32x4 b = *(const f32x4*)(p+4);
  #pragma unroll
  for (int j=0;j<4;j++){ f[j]=a[j]; f[4+j]=b[j]; }
}
__device__ __forceinline__ void load8(const short* p, float* f){
  bf16x8 v = *(const bf16x8*)p;
  #pragma unroll
  for (int j=0;j<8;j++) f[j]=bf2f(v[j]);
}
__device__ __forceinline__ float ldval(const float* p, size_t i){ return p[i]; }
__device__ __forceinline__ float ldval(const short* p, size_t i){ return bf2f(p[i]); }
__device__ __forceinline__ void stval(float* p, size_t i, float v){ p[i]=v; }
__device__ __forceinline__ void stval(short* p, size_t i, float v){ p[i]=f2bf(v); }

// ------------- transpose: W (KxN fp32) -> WT (NxK bf16) -------------
__global__ __launch_bounds__(256) void transpose_bf(const float* __restrict__ W,
                                                    short* __restrict__ WT, int K, int N){
  __shared__ float tile[32][33];
  int n0 = blockIdx.x*32, k0 = blockIdx.y*32;
  int tx = threadIdx.x, ty = threadIdx.y; // 32 x 8
  #pragma unroll
  for (int i=0;i<32;i+=8)
    tile[ty+i][tx] = W[(size_t)(k0+ty+i)*N + n0+tx];
  __syncthreads();
  #pragma unroll
  for (int i=0;i<32;i+=8)
    WT[(size_t)(n0+ty+i)*K + k0+tx] = f2bf(tile[tx][ty+i]);
}

// ------- transpose V: (B,S,H,HD) bf16 -> VT (B*H, HD, S) bf16 -------
__global__ __launch_bounds__(256) void transpose_v(const short* __restrict__ V,
                                                   short* __restrict__ VT){
  __shared__ short tile[32][33];
  int d0 = blockIdx.x*32, s0 = blockIdx.y*32, bh = blockIdx.z;
  int b = bh >> 3, h = bh & (H_-1);
  const short* Vp = V + (size_t)b*S_*D_ + (size_t)h*HD_;
  short* VTp = VT + (size_t)bh*HD_*S_;
  int tx = threadIdx.x, ty = threadIdx.y;
  #pragma unroll
  for (int i=0;i<32;i+=8)
    tile[ty+i][tx] = Vp[(size_t)(s0+ty+i)*D_ + d0+tx];   // tile[s][d]
  __syncthreads();
  #pragma unroll
  for (int i=0;i<32;i+=8)
    VTp[(size_t)(d0+ty+i)*S_ + s0+tx] = tile[tx][ty+i];
}

// ---------- LayerNorm over D=512, one wave per token, out bf16 ----------
template<typename TIn>
__global__ __launch_bounds__(256) void ln_kernel(const TIn* __restrict__ X,
                                                 const float* __restrict__ G,
                                                 const float* __restrict__ Bt,
                                                 short* __restrict__ O){
  int wid = threadIdx.x>>6, lane = threadIdx.x&63;
  int tok = blockIdx.x*4 + wid;
  const TIn* xp = X + (size_t)tok*D_;
  float f[8]; load8(xp + lane*8, f);
  float s=0.f, s2=0.f;
  #pragma unroll
  for (int j=0;j<8;j++){ s+=f[j]; s2+=f[j]*f[j]; }
  #pragma unroll
  for (int m=1;m<64;m<<=1){ s += __shfl_xor(s,m); s2 += __shfl_xor(s2,m); }
  float mu = s*(1.f/D_);
  float var = s2*(1.f/D_) - mu*mu;
  float rr = rsqrtf(var + EPS_);
  f32x4 g0 = *(const f32x4*)(G + lane*8), g1v = *(const f32x4*)(G + lane*8 + 4);
  f32x4 b0 = *(const f32x4*)(Bt + lane*8), b1v = *(const f32x4*)(Bt + lane*8 + 4);
  bf16x8 o;
  #pragma unroll
  for (int j=0;j<4;j++){
    o[j]   = f2bf((f[j]-mu)*rr*g0[j]  + b0[j]);
    o[4+j] = f2bf((f[4+j]-mu)*rr*g1v[j] + b1v[j]);
  }
  *(bf16x8*)(O + (size_t)tok*D_ + lane*8) = o;
}

// ---- GEMM: C = A(MxK,bf16) * BT(NxK,bf16)^T + bias(fp32), epilogue ----
// EPI: 0 = bias only; 1 = bias + residual; 2 = bias + exact GELU
template<int EPI, typename TR, typename TO>
__global__ __launch_bounds__(256) void gemm_bt(const short* __restrict__ A,
                                               const short* __restrict__ BT,
                                               const float* __restrict__ bias,
                                               const TR* __restrict__ res,
                                               TO* __restrict__ out,
                                               int M, int N, int K){
  __shared__ short As[128][40];
  __shared__ short Bs[128][40];
  int m0 = blockIdx.y*128, n0 = blockIdx.x*128;
  int tid = threadIdx.x, lane = tid&63, wid = tid>>6;
  int wr = wid>>1, wc = wid&1;
  int r = lane&15, kk = (lane>>4)*8;
  int arow = tid>>2, acol = (tid&3)*8;
  f32x4 zero = {0.f,0.f,0.f,0.f};
  f32x4 acc[4][4];
  #pragma unroll
  for (int i=0;i<4;i++)
    #pragma unroll
    for (int j=0;j<4;j++) acc[i][j] = zero;

  for (int k0=0;k0<K;k0+=32){
    __syncthreads();
    *(bf16x8*)&As[arow][acol]    = *(const bf16x8*)&A [(size_t)(m0+arow)*K    + k0+acol];
    *(bf16x8*)&As[arow+64][acol] = *(const bf16x8*)&A [(size_t)(m0+arow+64)*K + k0+acol];
    *(bf16x8*)&Bs[arow][acol]    = *(const bf16x8*)&BT[(size_t)(n0+arow)*K    + k0+acol];
    *(bf16x8*)&Bs[arow+64][acol] = *(const bf16x8*)&BT[(size_t)(n0+arow+64)*K + k0+acol];
    __syncthreads();
    bf16x8 a[4], b[4];
    #pragma unroll
    for (int i=0;i<4;i++) a[i] = *(const bf16x8*)&As[wr*64+i*16+r][kk];
    #pragma unroll
    for (int i=0;i<4;i++) b[i] = *(const bf16x8*)&Bs[wc*64+i*16+r][kk];
    #pragma unroll
    for (int mi=0;mi<4;mi++)
      #pragma unroll
      for (int ni=0;ni<4;ni++)
        acc[mi][ni] = __builtin_amdgcn_mfma_f32_16x16x32_bf16(a[mi], b[ni], acc[mi][ni], 0,0,0);
  }
  #pragma unroll
  for (int mi=0;mi<4;mi++){
    #pragma unroll
    for (int ni=0;ni<4;ni++){
      int col = n0 + wc*64 + ni*16 + r;
      float bs = bias[col];
      #pragma unroll
      for (int j=0;j<4;j++){
        int row = m0 + wr*64 + mi*16 + (lane>>4)*4 + j;
        float v = acc[mi][ni][j] + bs;
        if (EPI==1) v += ldval(res, (size_t)row*N + col);
        if (EPI==2) v = 0.5f*v*(1.f + erff(v*0.70710678118f));
        stval(out, (size_t)row*N + col, v);
      }
    }
  }
}

// -------- attention: per block = 64 q-rows of one (b,h); attn out fp32 --------
__global__ __launch_bounds__(256) void attn_kernel(const short* __restrict__ Q,
                                                   const short* __restrict__ Kt,
                                                   const short* __restrict__ VT,
                                                   float* __restrict__ attn_o,
                                                   short* __restrict__ ctx){
  __shared__ float plds[4][16][36];
  int wid = threadIdx.x>>6, lane = threadIdx.x&63;
  int bh = blockIdx.y, b = bh>>3, h = bh&7;
  int q0 = blockIdx.x*64 + wid*16;
  int r = lane&15, qh = lane>>4;
  const short* Qp = Q  + (size_t)b*S_*D_ + (size_t)h*HD_;
  const short* Kp = Kt + (size_t)b*S_*D_ + (size_t)h*HD_;
  const short* Vp = VT + (size_t)bh*HD_*S_;
  float* Ap = attn_o + (size_t)bh*S_*S_;

  bf16x8 aq0 = *(const bf16x8*)&Qp[(size_t)(q0+r)*D_ + qh*8];
  bf16x8 aq1 = *(const bf16x8*)&Qp[(size_t)(q0+r)*D_ + 32 + qh*8];

  f32x4 zero = {0.f,0.f,0.f,0.f};
  float part[4] = {0.f,0.f,0.f,0.f};
  for (int sc=0; sc<S_; sc+=32){
    bf16x8 k00 = *(const bf16x8*)&Kp[(size_t)(sc+r)*D_ + qh*8];
    bf16x8 k01 = *(const bf16x8*)&Kp[(size_t)(sc+r)*D_ + 32 + qh*8];
    bf16x8 k10 = *(const bf16x8*)&Kp[(size_t)(sc+16+r)*D_ + qh*8];
    bf16x8 k11 = *(const bf16x8*)&Kp[(size_t)(sc+16+r)*D_ + 32 + qh*8];
    f32x4 s0 = zero, s1 = zero;
    s0 = __builtin_amdgcn_mfma_f32_16x16x32_bf16(aq0, k00, s0, 0,0,0);
    s0 = __builtin_amdgcn_mfma_f32_16x16x32_bf16(aq1, k01, s0, 0,0,0);
    s1 = __builtin_amdgcn_mfma_f32_16x16x32_bf16(aq0, k10, s1, 0,0,0);
    s1 = __builtin_amdgcn_mfma_f32_16x16x32_bf16(aq1, k11, s1, 0,0,0);
    #pragma unroll
    for (int j=0;j<4;j++)
      part[j] += __expf(s0[j]*0.125f) + __expf(s1[j]*0.125f);
  }
  #pragma unroll
  for (int m=1;m<16;m<<=1){
    #pragma unroll
    for (int j=0;j<4;j++) part[j] += __shfl_xor(part[j], m);
  }
  float invl[4];
  #pragma unroll
  for (int j=0;j<4;j++) invl[j] = 1.f/part[j];

  f32x4 cacc[4];
  #pragma unroll
  for (int n=0;n<4;n++) cacc[n] = zero;

  for (int sc=0; sc<S_; sc+=32){
    bf16x8 k00 = *(const bf16x8*)&Kp[(size_t)(sc+r)*D_ + qh*8];
    bf16x8 k01 = *(const bf16x8*)&Kp[(size_t)(sc+r)*D_ + 32 + qh*8];
    bf16x8 k10 = *(const bf16x8*)&Kp[(size_t)(sc+16+r)*D_ + qh*8];
    bf16x8 k11 = *(const bf16x8*)&Kp[(size_t)(sc+16+r)*D_ + 32 + qh*8];
    f32x4 s0 = zero, s1 = zero;
    s0 = __builtin_amdgcn_mfma_f32_16x16x32_bf16(aq0, k00, s0, 0,0,0);
    s0 = __builtin_amdgcn_mfma_f32_16x16x32_bf16(aq1, k01, s0, 0,0,0);
    s1 = __builtin_amdgcn_mfma_f32_16x16x32_bf16(aq0, k10, s1, 0,0,0);
    s1 = __builtin_amdgcn_mfma_f32_16x16x32_bf16(aq1, k11, s1, 0,0,0);
    #pragma unroll
    for (int j=0;j<4;j++){
      plds[wid][qh*4+j][r]      = __expf(s0[j]*0.125f)*invl[j];
      plds[wid][qh*4+j][16+r]   = __expf(s1[j]*0.125f)*invl[j];
    }
    __syncthreads();
    // coalesced fp32 attn store: 4 lanes cover one row's 32 cols (128B)
    {
      int rr2 = lane>>2, cc = (lane&3)*8;
      f32x4 o0, o1;
      #pragma unroll
      for (int c=0;c<4;c++){ o0[c]=plds[wid][rr2][cc+c]; o1[c]=plds[wid][rr2][cc+4+c]; }
      float* dst = &Ap[(size_t)(q0+rr2)*S_ + sc + cc];
      *(f32x4*)dst = o0;
      *(f32x4*)(dst+4) = o1;
    }
    // P A-fragment for PV mfma
    bf16x8 pa;
    #pragma unroll
    for (int c=0;c<8;c++) pa[c] = f2bf(plds[wid][r][qh*8+c]);
    #pragma unroll
    for (int n=0;n<4;n++){
      bf16x8 vb = *(const bf16x8*)&Vp[(size_t)(n*16+r)*S_ + sc + qh*8];
      cacc[n] = __builtin_amdgcn_mfma_f32_16x16x32_bf16(pa, vb, cacc[n], 0,0,0);
    }
  }
  #pragma unroll
  for (int n=0;n<4;n++)
    #pragma unroll
    for (int j=0;j<4;j++)
      ctx[(size_t)(b*S_ + q0 + qh*4 + j)*D_ + h*HD_ + n*16 + r] = f2bf(cacc[n][j]);
}

// --------------------------------- host ---------------------------------
extern "C" void kernel_launch(void* const* d_in, const int* in_sizes, int n_in,
                              void* d_out, int out_size, void* d_ws, size_t ws_size,
                              hipStream_t stream){
  const float* x   = (const float*)d_in[0];
  const float* Wq  = (const float*)d_in[1];
  const float* bq  = (const float*)d_in[2];
  const float* Wk  = (const float*)d_in[3];
  const float* bk  = (const float*)d_in[4];
  const float* Wv  = (const float*)d_in[5];
  const float* bv  = (const float*)d_in[6];
  const float* Wo  = (const float*)d_in[7];
  const float* bo  = (const float*)d_in[8];
  const float* W1  = (const float*)d_in[9];
  const float* b1  = (const float*)d_in[10];
  const float* W2  = (const float*)d_in[11];
  const float* b2  = (const float*)d_in[12];
  const float* g1  = (const float*)d_in[13];
  const float* be1 = (const float*)d_in[14];
  const float* g2  = (const float*)d_in[15];
  const float* be2 = (const float*)d_in[16];

  char* ws = (char*)d_ws;
  const size_t KB = 1024;
  short* wqT = (short*)(ws + 0*KB);
  short* wkT = (short*)(ws + 512*KB);
  short* wvT = (short*)(ws + 1024*KB);
  short* woT = (short*)(ws + 1536*KB);
  short* w1T = (short*)(ws + 2048*KB);    // 2 MB
  short* w2T = (short*)(ws + 4096*KB);    // 2 MB
  short* hbf = (short*)(ws + 6144*KB);    // 8 MB  (LN1 out; reused for LN2 out)
  short* Qb  = (short*)(ws + 14336*KB);   // 8 MB
  short* Kb  = (short*)(ws + 22528*KB);   // 8 MB
  short* Vb  = (short*)(ws + 30720*KB);   // 8 MB
  short* VTb = (short*)(ws + 38912*KB);   // 8 MB
  short* ctx = (short*)(ws + 47104*KB);   // 8 MB
  short* f1  = (short*)(ws + 14336*KB);   // 32 MB, aliases Q/K/V/VT (dead after attn)
  // total ws use: 54 MB

  float* out0 = (float*)d_out;                      // [8192,512] fp32; also holds x1
  float* attn = out0 + (size_t)NT_*D_;              // [16,4096,4096] fp32

  dim3 tb(32,8);
  transpose_bf<<<dim3(16,16),tb,0,stream>>>(Wq, wqT, 512, 512);
  transpose_bf<<<dim3(16,16),tb,0,stream>>>(Wk, wkT, 512, 512);
  transpose_bf<<<dim3(16,16),tb,0,stream>>>(Wv, wvT, 512, 512);
  transpose_bf<<<dim3(16,16),tb,0,stream>>>(Wo, woT, 512, 512);
  transpose_bf<<<dim3(64,16),tb,0,stream>>>(W1, w1T, 512, 2048);
  transpose_bf<<<dim3(16,64),tb,0,stream>>>(W2, w2T, 2048, 512);

  ln_kernel<float><<<NT_/4, 256, 0, stream>>>(x, g1, be1, hbf);

  gemm_bt<0,float,short><<<dim3(4,64),256,0,stream>>>(hbf, wqT, bq, nullptr, Qb, NT_, 512, 512);
  gemm_bt<0,float,short><<<dim3(4,64),256,0,stream>>>(hbf, wkT, bk, nullptr, Kb, NT_, 512, 512);
  gemm_bt<0,float,short><<<dim3(4,64),256,0,stream>>>(hbf, wvT, bv, nullptr, Vb, NT_, 512, 512);

  transpose_v<<<dim3(2,128,16),tb,0,stream>>>(Vb, VTb);

  attn_kernel<<<dim3(64,16),256,0,stream>>>(Qb, Kb, VTb, attn, ctx);

  // x1 = x + ctx@Wo + bo   -> stored fp32 in out0
  gemm_bt<1,float,float><<<dim3(4,64),256,0,stream>>>(ctx, woT, bo, x, out0, NT_, 512, 512);

  ln_kernel<float><<<NT_/4, 256, 0, stream>>>(out0, g2, be2, hbf);

  gemm_bt<2,float,short><<<dim3(16,64),256,0,stream>>>(hbf, w1T, b1, nullptr, f1, NT_, 2048, 512);

  // out = x1 + f1@W2 + b2  (in-place residual read from out0 is per-element safe)
  gemm_bt<1,float,float><<<dim3(4,64),256,0,stream>>>(f1, w2T, b2, out0, out0, NT_, 512, 2048);
}